// Round 5
// baseline (240.850 us; speedup 1.0000x reference)
//
#include <hip/hip_runtime.h>

// Problem constants (from reference)
#define B_ROWS  32768
#define S_SAMP  16
#define NRELS   238
#define DIM     256
#define N_NODES 100000
#define NF4     ((N_NODES * DIM) / 4)     // 6,400,000 float4 elements of F
#define CONV_BLOCKS (NF4 / 256)           // 25,000

typedef __attribute__((ext_vector_type(8))) short  short8;    // 8 x bf16 (4 VGPRs)
typedef __attribute__((ext_vector_type(4))) float  f32x4;     // MFMA accumulator

static __device__ __forceinline__ unsigned short f2bf(float f) {
    unsigned int u = __float_as_uint(f);
    u += 0x7FFFu + ((u >> 16) & 1u);   // round-to-nearest-even
    return (unsigned short)(u >> 16);
}
static __device__ __forceinline__ float bf2f(unsigned short u) {
    return __uint_as_float(((unsigned int)u) << 16);
}

// Kernel 1 (prep): blocks [0,CONV_BLOCKS) stream-convert F fp32 -> Fb bf16.
// Remaining blocks build Wb = bf16(W) (row-major [n][k] == MFMA B-frag layout)
// and RWTb = bf16(relation_weight^T) [238][256] (contiguous gather rows).
__global__ __launch_bounds__(256) void prep_kernel(const float* __restrict__ F,
                                                   const float* __restrict__ W,
                                                   const float* __restrict__ RW,
                                                   unsigned short* __restrict__ Fb,
                                                   unsigned short* __restrict__ Wb,
                                                   unsigned short* __restrict__ RWTb) {
    if (blockIdx.x < CONV_BLOCKS) {
        int i = blockIdx.x * 256 + threadIdx.x;       // float4 index
        float4 v = ((const float4*)F)[i];
        ushort4 p;
        p.x = f2bf(v.x); p.y = f2bf(v.y); p.z = f2bf(v.z); p.w = f2bf(v.w);
        ((ushort4*)Fb)[i] = p;
    } else {
        int i = (blockIdx.x - CONV_BLOCKS) * 256 + threadIdx.x;
        if (i < DIM * DIM) Wb[i] = f2bf(W[i]);
        if (i < NRELS * DIM) {
            int r = i >> 8;      // relation id
            int d = i & 255;     // output dim
            RWTb[i] = f2bf(RW[d * NRELS + r]);
        }
    }
}

// Kernel 2 (fused main): one block = 32 output rows.
// Phase 1: 4 waves x 8 rows; per row, 16 neighbor-row gathers (bf16, 512B row
//   = 64 lanes x ushort4) + 16 relation-row gathers, fp32 mean (x1/16 folded),
//   bf16 results into LDS As (aggregated features) and Rs (relation mean).
// Phase 2: wave `wid` owns n-tiles wid*4..wid*4+3 with B-fragments preloaded
//   into 128 VGPRs (between phase 1 and the barrier, so the L2 loads overlap);
//   2 m-tiles x 8 k-steps of 16x16x32 bf16 MFMA off the padded LDS tile
//   (row stride 264 ushorts = 4-bank rotation -> only free 2-way conflicts).
// Epilogue: + Rs, ReLU, fp32 store.
__global__ __launch_bounds__(256) void fused_kernel(const int* __restrict__ nbr,
                                                    const int* __restrict__ rels,
                                                    const unsigned short* __restrict__ Fb,
                                                    const unsigned short* __restrict__ RWTb,
                                                    const unsigned short* __restrict__ Wb,
                                                    float* __restrict__ out) {
    __shared__ unsigned short As[32][264];
    __shared__ unsigned short Rs[32][264];
    const int tid  = threadIdx.x;
    const int lane = tid & 63;
    const int wid  = __builtin_amdgcn_readfirstlane(tid >> 6);   // 0..3
    const int col0 = lane & 15;
    const int quad = lane >> 4;
    const int r0g  = blockIdx.x * 32;

    // ---- Phase 1: gather + mean ----
    const float sc = 1.0f / 16.0f;
    for (int i = 0; i < 8; ++i) {
        const int row_l = wid * 8 + i;
        const int row_g = r0g + row_l;
        const int2* nb2 = (const int2*)(nbr  + row_g * S_SAMP);  // wave-uniform -> s_load
        const int2* rl2 = (const int2*)(rels + row_g * S_SAMP);
        float a0 = 0.f, a1 = 0.f, a2 = 0.f, a3 = 0.f;
        float b0 = 0.f, b1 = 0.f, b2 = 0.f, b3 = 0.f;
#pragma unroll
        for (int t = 0; t < 8; ++t) {
            int2 nn = nb2[t];
            int2 rr = rl2[t];
            ushort4 f0 = *(const ushort4*)(Fb   + (size_t)nn.x * DIM + lane * 4);
            ushort4 g0 = *(const ushort4*)(RWTb + (size_t)rr.x * DIM + lane * 4);
            ushort4 f1 = *(const ushort4*)(Fb   + (size_t)nn.y * DIM + lane * 4);
            ushort4 g1 = *(const ushort4*)(RWTb + (size_t)rr.y * DIM + lane * 4);
            a0 += bf2f(f0.x) + bf2f(f1.x);
            a1 += bf2f(f0.y) + bf2f(f1.y);
            a2 += bf2f(f0.z) + bf2f(f1.z);
            a3 += bf2f(f0.w) + bf2f(f1.w);
            b0 += bf2f(g0.x) + bf2f(g1.x);
            b1 += bf2f(g0.y) + bf2f(g1.y);
            b2 += bf2f(g0.z) + bf2f(g1.z);
            b3 += bf2f(g0.w) + bf2f(g1.w);
        }
        ushort4 pa, pr;
        pa.x = f2bf(a0 * sc); pa.y = f2bf(a1 * sc); pa.z = f2bf(a2 * sc); pa.w = f2bf(a3 * sc);
        pr.x = f2bf(b0 * sc); pr.y = f2bf(b1 * sc); pr.z = f2bf(b2 * sc); pr.w = f2bf(b3 * sc);
        *(ushort4*)&As[row_l][lane * 4] = pa;
        *(ushort4*)&Rs[row_l][lane * 4] = pr;
    }

    // Preload B fragments (L2-resident Wb) — placed here so the loads drain
    // during the barrier wait instead of serializing the MFMA loop.
    short8 Breg[4][8];
#pragma unroll
    for (int j = 0; j < 4; ++j) {
#pragma unroll
        for (int kk = 0; kk < 8; ++kk) {
            int n = wid * 4 + j;
            Breg[j][kk] = *(const short8*)(Wb + (size_t)(n * 16 + col0) * DIM
                                              + kk * 32 + quad * 8);
        }
    }
    __syncthreads();

    // ---- Phase 2: 32x64 output tile per wave via MFMA ----
    f32x4 acc[2][4];
#pragma unroll
    for (int mt = 0; mt < 2; ++mt)
#pragma unroll
        for (int j = 0; j < 4; ++j) acc[mt][j] = (f32x4){0.f, 0.f, 0.f, 0.f};

#pragma unroll
    for (int mt = 0; mt < 2; ++mt) {
        const int mrow = mt * 16 + col0;
#pragma unroll
        for (int kk = 0; kk < 8; ++kk) {
            short8 af = *(const short8*)&As[mrow][kk * 32 + quad * 8];
#pragma unroll
            for (int j = 0; j < 4; ++j)
                acc[mt][j] = __builtin_amdgcn_mfma_f32_16x16x32_bf16(af, Breg[j][kk], acc[mt][j], 0, 0, 0);
        }
    }

    // ---- Epilogue: + rel mean, ReLU, store ----
#pragma unroll
    for (int mt = 0; mt < 2; ++mt) {
#pragma unroll
        for (int j = 0; j < 4; ++j) {
            const int col = (wid * 4 + j) * 16 + col0;
#pragma unroll
            for (int i2 = 0; i2 < 4; ++i2) {
                const int r_l = mt * 16 + quad * 4 + i2;
                float v = acc[mt][j][i2] + bf2f(Rs[r_l][col]);
                out[(size_t)(r0g + r_l) * DIM + col] = v > 0.f ? v : 0.f;
            }
        }
    }
}

extern "C" void kernel_launch(void* const* d_in, const int* in_sizes, int n_in,
                              void* d_out, int out_size, void* d_ws, size_t ws_size,
                              hipStream_t stream) {
    const int*   neighbors = (const int*)d_in[0];
    const int*   relations = (const int*)d_in[1];
    const float* features  = (const float*)d_in[2];
    const float* weight    = (const float*)d_in[3];
    const float* relw      = (const float*)d_in[4];
    float* out = (float*)d_out;

    char* ws = (char*)d_ws;
    // ws layout (bytes): Wb   bf16 [256*256]    at 0       (131072)
    //                    RWTb bf16 [238*256]    at 131072  (121856)
    //                    Fb   bf16 [100000*256] at 253952  (51200000)  ~51.5 MB
    unsigned short* Wb   = (unsigned short*)ws;
    unsigned short* RWTb = (unsigned short*)(ws + 131072);
    unsigned short* Fb   = (unsigned short*)(ws + 253952);

    prep_kernel<<<CONV_BLOCKS + 256, 256, 0, stream>>>(features, weight, relw, Fb, Wb, RWTb);
    fused_kernel<<<B_ROWS / 32, 256, 0, stream>>>(neighbors, relations, Fb, RWTb, Wb, out);
}

// Round 6
// 217.508 us; speedup vs baseline: 1.1073x; 1.1073x over previous
//
#include <hip/hip_runtime.h>

// Problem constants (from reference)
#define B_ROWS  32768
#define S_SAMP  16
#define NRELS   238
#define DIM     256
#define N_NODES 100000
#define NF4     ((N_NODES * DIM) / 4)     // 6,400,000 float4 elements of F
#define CONV_BLOCKS (NF4 / 256)           // 25,000

typedef __attribute__((ext_vector_type(8))) short  short8;    // 8 x bf16 (4 VGPRs)
typedef __attribute__((ext_vector_type(8))) unsigned short ushort8;
typedef __attribute__((ext_vector_type(4))) float  f32x4;     // MFMA accumulator

static __device__ __forceinline__ unsigned short f2bf(float f) {
    unsigned int u = __float_as_uint(f);
    u += 0x7FFFu + ((u >> 16) & 1u);   // round-to-nearest-even
    return (unsigned short)(u >> 16);
}
static __device__ __forceinline__ float bf2f(unsigned short u) {
    return __uint_as_float(((unsigned int)u) << 16);
}

// Kernel 1 (prep): blocks [0,CONV_BLOCKS) stream-convert F fp32 -> Fb bf16.
// Remaining blocks build Wb = bf16(W) (row-major [n][k] == MFMA B-frag layout)
// and RWTb = bf16(relation_weight^T) [238][256] (contiguous gather rows).
__global__ __launch_bounds__(256) void prep_kernel(const float* __restrict__ F,
                                                   const float* __restrict__ W,
                                                   const float* __restrict__ RW,
                                                   unsigned short* __restrict__ Fb,
                                                   unsigned short* __restrict__ Wb,
                                                   unsigned short* __restrict__ RWTb) {
    if (blockIdx.x < CONV_BLOCKS) {
        int i = blockIdx.x * 256 + threadIdx.x;       // float4 index
        float4 v = ((const float4*)F)[i];
        ushort4 p;
        p.x = f2bf(v.x); p.y = f2bf(v.y); p.z = f2bf(v.z); p.w = f2bf(v.w);
        ((ushort4*)Fb)[i] = p;
    } else {
        int i = (blockIdx.x - CONV_BLOCKS) * 256 + threadIdx.x;
        if (i < DIM * DIM) Wb[i] = f2bf(W[i]);
        if (i < NRELS * DIM) {
            int r = i >> 8;      // relation id
            int d = i & 255;     // output dim
            RWTb[i] = f2bf(RW[d * NRELS + r]);
        }
    }
}

// Kernel 2 (fused main): one block = 32 output rows, 4 waves.
// Phase 1 (gather+mean): per row, lanes 0-31 process even samples / 32-63 odd;
//   each lane loads 16B (8 dims) per sample -> 8 feature + 8 relation loads
//   per row (HALF the load instructions of 8B/lane). One shfl_xor(32) per
//   value merges halves (each lane sends the partial its partner needs).
//   Lanes<32 pack bf16 feature means -> As; lanes>=32 pack rel means -> Rs.
// Phase 2: wave `wid` owns n-tiles wid*4..wid*4+3; B-fragments preloaded in
//   TWO sequential Breg[4][4] batches (peak 64 VGPRs, enabling 4 blocks/CU
//   under __launch_bounds__(256,4)); 2 m-tiles x 8 k-steps of 16x16x32 MFMA
//   off the padded LDS tile (row stride 264 ushorts -> free 2-way conflicts).
// Epilogue: + Rs, ReLU, fp32 store.
__global__ __launch_bounds__(256, 4) void fused_kernel(const int* __restrict__ nbr,
                                                       const int* __restrict__ rels,
                                                       const unsigned short* __restrict__ Fb,
                                                       const unsigned short* __restrict__ RWTb,
                                                       const unsigned short* __restrict__ Wb,
                                                       float* __restrict__ out) {
    __shared__ unsigned short As[32][264];
    __shared__ unsigned short Rs[32][264];
    const int tid  = threadIdx.x;
    const int lane = tid & 63;
    const int wid  = __builtin_amdgcn_readfirstlane(tid >> 6);   // 0..3
    const int half = lane >> 5;       // 0: even samples, 1: odd samples
    const int li   = lane & 31;       // 16B chunk: dims [li*8, li*8+8)
    const int col0 = lane & 15;
    const int quad = lane >> 4;
    const int r0g  = blockIdx.x * 32;

    // ---- Phase 1: gather + mean ----
    const float sc = 1.0f / 16.0f;
    for (int i = 0; i < 8; ++i) {
        const int row_l = wid * 8 + i;
        const int row_g = r0g + row_l;
        const int2* nb2 = (const int2*)(nbr  + row_g * S_SAMP);  // wave-uniform -> s_load
        const int2* rl2 = (const int2*)(rels + row_g * S_SAMP);
        float af[8] = {0.f, 0.f, 0.f, 0.f, 0.f, 0.f, 0.f, 0.f};
        float ag[8] = {0.f, 0.f, 0.f, 0.f, 0.f, 0.f, 0.f, 0.f};
#pragma unroll
        for (int t = 0; t < 8; ++t) {
            int2 nn = nb2[t];
            int2 rr = rl2[t];
            int nid = half ? nn.y : nn.x;
            int rid = half ? rr.y : rr.x;
            ushort8 f = *(const ushort8*)(Fb   + (size_t)nid * DIM + li * 8);
            ushort8 g = *(const ushort8*)(RWTb + (size_t)rid * DIM + li * 8);
#pragma unroll
            for (int j = 0; j < 8; ++j) { af[j] += bf2f(f[j]); ag[j] += bf2f(g[j]); }
        }
        // Cross-half merge: each lane keeps the partial it will store and
        // sends the one its partner needs -> ONE shfl per value.
        ushort8 pk;
#pragma unroll
        for (int j = 0; j < 8; ++j) {
            float mine = half ? ag[j] : af[j];
            float send = half ? af[j] : ag[j];
            float full = mine + __shfl_xor(send, 32, 64);
            pk[j] = f2bf(full * sc);
        }
        unsigned short* dst = half ? &Rs[row_l][li * 8] : &As[row_l][li * 8];
        *(ushort8*)dst = pk;
    }

    // ---- B preload batch 1 (k 0..127), overlaps barrier wait ----
    short8 Breg[4][4];
#pragma unroll
    for (int j = 0; j < 4; ++j)
#pragma unroll
        for (int kk = 0; kk < 4; ++kk)
            Breg[j][kk] = *(const short8*)(Wb + (size_t)((wid * 4 + j) * 16 + col0) * DIM
                                              + kk * 32 + quad * 8);
    __syncthreads();

    // ---- Phase 2: 32x64 output tile per wave via MFMA ----
    f32x4 acc[2][4];
#pragma unroll
    for (int mt = 0; mt < 2; ++mt)
#pragma unroll
        for (int j = 0; j < 4; ++j) acc[mt][j] = (f32x4){0.f, 0.f, 0.f, 0.f};

#pragma unroll
    for (int mt = 0; mt < 2; ++mt) {
        const int mrow = mt * 16 + col0;
#pragma unroll
        for (int kk = 0; kk < 4; ++kk) {
            short8 a = *(const short8*)&As[mrow][kk * 32 + quad * 8];
#pragma unroll
            for (int j = 0; j < 4; ++j)
                acc[mt][j] = __builtin_amdgcn_mfma_f32_16x16x32_bf16(a, Breg[j][kk], acc[mt][j], 0, 0, 0);
        }
    }
    // ---- B preload batch 2 (k 128..255), then finish K ----
#pragma unroll
    for (int j = 0; j < 4; ++j)
#pragma unroll
        for (int kk = 0; kk < 4; ++kk)
            Breg[j][kk] = *(const short8*)(Wb + (size_t)((wid * 4 + j) * 16 + col0) * DIM
                                              + (kk + 4) * 32 + quad * 8);
#pragma unroll
    for (int mt = 0; mt < 2; ++mt) {
        const int mrow = mt * 16 + col0;
#pragma unroll
        for (int kk = 0; kk < 4; ++kk) {
            short8 a = *(const short8*)&As[mrow][(kk + 4) * 32 + quad * 8];
#pragma unroll
            for (int j = 0; j < 4; ++j)
                acc[mt][j] = __builtin_amdgcn_mfma_f32_16x16x32_bf16(a, Breg[j][kk], acc[mt][j], 0, 0, 0);
        }
    }

    // ---- Epilogue: + rel mean, ReLU, store ----
#pragma unroll
    for (int mt = 0; mt < 2; ++mt) {
#pragma unroll
        for (int j = 0; j < 4; ++j) {
            const int col = (wid * 4 + j) * 16 + col0;
#pragma unroll
            for (int i2 = 0; i2 < 4; ++i2) {
                const int r_l = mt * 16 + quad * 4 + i2;
                float v = acc[mt][j][i2] + bf2f(Rs[r_l][col]);
                out[(size_t)(r0g + r_l) * DIM + col] = v > 0.f ? v : 0.f;
            }
        }
    }
}

extern "C" void kernel_launch(void* const* d_in, const int* in_sizes, int n_in,
                              void* d_out, int out_size, void* d_ws, size_t ws_size,
                              hipStream_t stream) {
    const int*   neighbors = (const int*)d_in[0];
    const int*   relations = (const int*)d_in[1];
    const float* features  = (const float*)d_in[2];
    const float* weight    = (const float*)d_in[3];
    const float* relw      = (const float*)d_in[4];
    float* out = (float*)d_out;

    char* ws = (char*)d_ws;
    // ws layout (bytes): Wb   bf16 [256*256]    at 0       (131072)
    //                    RWTb bf16 [238*256]    at 131072  (121856)
    //                    Fb   bf16 [100000*256] at 253952  (51200000)  ~51.5 MB
    unsigned short* Wb   = (unsigned short*)ws;
    unsigned short* RWTb = (unsigned short*)(ws + 131072);
    unsigned short* Fb   = (unsigned short*)(ws + 253952);

    prep_kernel<<<CONV_BLOCKS + 256, 256, 0, stream>>>(features, weight, relw, Fb, Wb, RWTb);
    fused_kernel<<<B_ROWS / 32, 256, 0, stream>>>(neighbors, relations, Fb, RWTb, Wb, out);
}